// Round 1
// baseline (80.937 us; speedup 1.0000x reference)
//
#include <hip/hip_runtime.h>

// DTW via min-plus scan for MI355X (gfx950). Round 15.
// B=32, N=32, D=12, P=32, L=1024, L_OUT=32, RHO=1 => w=1.
// r15: split each (b,n) across TWO waves (8 cols/lane), pipelined with a
// 2-row skew and LDS handoff of {scan-total Z, S[511], D[511]} per row.
//   - 2 waves/SIMD (2048 waves / 1024 SIMDs): partner wave's independent
//     S-FMAs cover the serial min-scan dependency stalls that a single
//     wave/EU fully exposes (r13->r14 neutrality despite halved FMA count
//     says we are stall-bound, not issue-bound).
//   - per-wave VGPR ~180 (SXp 12x4 v2f = 96) -- well under the 256 budget
//     for 2 waves/EU; kills any scratch-spill risk of the ~500-reg r14 shape.
//   - intra-lane serial min-chain depth halved (15 -> 7).

#define BIGF 1e30f
#define LL   1024
#define LOUT 32

using v4f = __attribute__((ext_vector_type(4))) float;
using v2f = __attribute__((ext_vector_type(2))) float;

__device__ __forceinline__ v2f fma2(v2f a, v2f b, v2f c) {
    return __builtin_elementwise_fma(a, b, c);
}
__device__ __forceinline__ v2f bc2(float s) { v2f r = {s, s}; return r; }

template<int CTRL>
__device__ __forceinline__ float dpp_self(float v) {   // invalid lanes keep own
    return __int_as_float(__builtin_amdgcn_update_dpp(
        __float_as_int(v), __float_as_int(v), CTRL, 0xF, 0xF, false));
}
template<int CTRL>
__device__ __forceinline__ float dpp_zero(float v) {   // invalid lanes get 0
    return __int_as_float(__builtin_amdgcn_update_dpp(
        0, __float_as_int(v), CTRL, 0xF, 0xF, false));
}
// validated r2-r14: whole-wave shift right 1 lane; lane 0 <- 0
__device__ __forceinline__ float wshr1z(float v) {
    return __int_as_float(__builtin_amdgcn_update_dpp(
        0, __float_as_int(v), 0x138 /*wave_shr:1*/, 0xF, 0xF, false));
}
__device__ __forceinline__ float rdlane(float v, int l) {
    return __int_as_float(__builtin_amdgcn_readlane(__float_as_int(v), l));
}

// inclusive wave64 min-scan (validated r9-r14)
__device__ __forceinline__ float scan_min64_fast(float t, int lane) {
    t = fminf(t, dpp_self<0x111>(t));   // row_shr:1
    t = fminf(t, dpp_self<0x112>(t));   // row_shr:2
    t = fminf(t, dpp_self<0x114>(t));   // row_shr:4
    t = fminf(t, dpp_self<0x118>(t));   // row_shr:8
    float r0 = rdlane(t, 15), r1 = rdlane(t, 31), r2 = rdlane(t, 47);
    t = fminf(t, (lane >= 16) ? r0 : BIGF);
    t = fminf(t, (lane >= 32) ? r1 : BIGF);
    t = fminf(t, (lane >= 48) ? r2 : BIGF);
    return t;
}
// inclusive wave64 add-scan (validated r14)
__device__ __forceinline__ float scan_add64_dpp(float t, int lane) {
    t += dpp_zero<0x111>(t);
    t += dpp_zero<0x112>(t);
    t += dpp_zero<0x114>(t);
    t += dpp_zero<0x118>(t);
    float r0 = rdlane(t, 15), r1 = rdlane(t, 31), r2 = rdlane(t, 47);
    t += (lane >= 16) ? r0 : 0.0f;
    t += (lane >= 32) ? r1 : 0.0f;
    t += (lane >= 48) ? r2 : 0.0f;
    return t;
}

__global__ __launch_bounds__(128, 2)   // 2 waves/EU: 256-VGPR budget, 2x hiding
void dtw_kernel(const float* __restrict__ x, const float* __restrict__ patts,
                float* __restrict__ out) {
    const int tid  = threadIdx.x;
    const int lane = tid & 63;
    const int wv   = tid >> 6;            // wave 0: cols 0..511, wave 1: 512..1023
    const bool l0  = (lane == 0);
    const int blk  = blockIdx.x;          // 0..1023 = (b,n)
    const int b    = blk >> 5, n = blk & 31;
    const float* __restrict__ xb = x + b * (12 * LL);
    const float* __restrict__ pn = patts + n * (12 * 32);

    __shared__ float ldsZ[32];   // wave0 row-i inclusive scan total over cols 0..511
    __shared__ float ldsS[32];   // S_i[511]
    __shared__ float ldsD[32];   // D_i[511]
    __shared__ float ldsT[16];   // setup: wave0 prefix-sum totals (12 x-dims + x^2)

    // ---- pattern params into registers: lane r (r&31) holds row r ----
    float prm[12], p2r;
    {
        const int r = lane & 31;
        float s2 = 0.f;
#pragma unroll
        for (int d = 0; d < 12; ++d) {
            float v = pn[d * 32 + r];
            s2 = fmaf(v, v, s2);
            prm[d] = -2.0f * v;
        }
        p2r = s2;
    }

    // ---- x half-slice -> packed regs (8 cols/lane, coalesced) ----
    const int colbase = (wv << 9) + (lane << 3);
    v2f SXp[12][4];
#pragma unroll
    for (int d = 0; d < 12; ++d) {
#pragma unroll
        for (int c = 0; c < 2; ++c) {
            v4f v = *(const v4f*)(xb + d * LL + colbase + 4 * c);
            v2f lo = {v.x, v.y}, hi = {v.z, v.w};
            SXp[d][2 * c]     = lo;
            SXp[d][2 * c + 1] = hi;
        }
    }
    v2f SX2p[4];
#pragma unroll
    for (int j = 0; j < 4; ++j) {
        v2f t = SXp[0][j] * SXp[0][j];
#pragma unroll
        for (int d = 1; d < 12; ++d) t = fma2(SXp[d][j], SXp[d][j], t);
        SX2p[j] = t;
    }
    // ---- per-wave inclusive prefix sums; wave0 publishes totals ----
#pragma unroll
    for (int d = 0; d < 12; ++d) {
        float run = 0.f;
#pragma unroll
        for (int j = 0; j < 4; ++j) {
            float a0 = SXp[d][j].x + run;
            float a1 = SXp[d][j].y + a0;
            SXp[d][j].x = a0; SXp[d][j].y = a1; run = a1;
        }
        float inc = scan_add64_dpp(run, lane);
        if (wv == 0 && lane == 63) ldsT[d] = inc;   // total over cols 0..511
        v2f exv = bc2(inc - run);
#pragma unroll
        for (int j = 0; j < 4; ++j) SXp[d][j] += exv;
    }
    {
        float run = 0.f;
#pragma unroll
        for (int j = 0; j < 4; ++j) {
            float a0 = SX2p[j].x + run;
            float a1 = SX2p[j].y + a0;
            SX2p[j].x = a0; SX2p[j].y = a1; run = a1;
        }
        float inc = scan_add64_dpp(run, lane);
        if (wv == 0 && lane == 63) ldsT[12] = inc;
        v2f exv = bc2(inc - run);
#pragma unroll
        for (int j = 0; j < 4; ++j) SX2p[j] += exv;
    }
    __syncthreads();
    if (wv == 1) {   // make wave1's prefix sums global
#pragma unroll
        for (int d = 0; d < 12; ++d) {
            v2f t = bc2(ldsT[d]);
#pragma unroll
            for (int j = 0; j < 4; ++j) SXp[d][j] += t;
        }
        v2f t2 = bc2(ldsT[12]);
#pragma unroll
        for (int j = 0; j < 4; ++j) SX2p[j] += t2;
    }

    v2f jp1p[4];
#pragma unroll
    for (int j = 0; j < 4; ++j) {
        v2f t = {(float)(colbase + 2 * j + 1), (float)(colbase + 2 * j + 2)};
        jp1p[j] = t;
    }

    v2f S2[4];
    float Dp[8];

#define COMPUTE_S(i) do { \
    float pv[12], p2u; \
    _Pragma("unroll") for (int d = 0; d < 12; ++d) pv[d] = rdlane(prm[d], (i)); \
    p2u = rdlane(p2r, (i)); \
    _Pragma("unroll") for (int j = 0; j < 4; ++j) \
        S2[j] = fma2(bc2(p2u), jp1p[j], SX2p[j]); \
    _Pragma("unroll") for (int d = 0; d < 12; ++d) { \
        v2f pb = bc2(pv[d]); \
        _Pragma("unroll") for (int j = 0; j < 4; ++j) \
            S2[j] = fma2(pb, SXp[d][j], S2[j]); \
    } \
} while (0)

#define ROW0() do { \
    COMPUTE_S(0); \
    _Pragma("unroll") for (int k = 0; k < 8; ++k) Dp[k] = S2[k >> 1][k & 1]; \
} while (0)

#define STORE_ROW(i) do { \
    if (lane >= 60) { \
        float* ob = out + blk * (32 * LOUT) + (i) * LOUT + (lane - 60) * 8; \
        v4f va = {Dp[0], Dp[1], Dp[2], Dp[3]}; \
        v4f vb = {Dp[4], Dp[5], Dp[6], Dp[7]}; \
        *(v4f*)ob = va; *(v4f*)(ob + 4) = vb; \
    } \
} while (0)

// wave0 general row: left global boundary, publish {Z, S[511], D[511]}
#define ROW_W0(i) do { \
    COMPUTE_S(i); \
    float dsh = wshr1z(Dp[7]); dsh = l0 ? BIGF : dsh; \
    float se  = wshr1z(S2[3].y);              /* lane0 -> 0 == S[-1] */ \
    float m[8]; \
    m[0] = fminf(dsh, Dp[0]) - se; \
    _Pragma("unroll") for (int k = 1; k < 8; ++k) \
        m[k] = fminf(m[k-1], \
                     fminf(Dp[k-1], Dp[k]) - S2[(k-1) >> 1][(k-1) & 1]); \
    float t = scan_min64_fast(m[7], lane); \
    float te = wshr1z(t); te = l0 ? BIGF : te; \
    _Pragma("unroll") for (int k = 0; k < 8; ++k) \
        Dp[k] = S2[k >> 1][k & 1] + fminf(te, m[k]); \
    if (lane == 63) { ldsZ[i] = t; ldsS[i] = S2[3].y; ldsD[i] = Dp[7]; } \
} while (0)

// wave1 general row: boundary scalars (Z0 = wave0 scan total of row i,
// Sb = S_i[511], Db = D_{i-1}[511]) come from LDS, read before the call.
#define ROW_W1(i, Z0, Sb, Db) do { \
    COMPUTE_S(i); \
    float dsh = wshr1z(Dp[7]); dsh = l0 ? (Db) : dsh; \
    float se  = wshr1z(S2[3].y); se = l0 ? (Sb) : se; \
    float m[8]; \
    m[0] = fminf(dsh, Dp[0]) - se; \
    _Pragma("unroll") for (int k = 1; k < 8; ++k) \
        m[k] = fminf(m[k-1], \
                     fminf(Dp[k-1], Dp[k]) - S2[(k-1) >> 1][(k-1) & 1]); \
    float t = scan_min64_fast(m[7], lane); \
    float te = wshr1z(t); te = l0 ? BIGF : te; \
    te = fminf(te, (Z0)); \
    _Pragma("unroll") for (int k = 0; k < 8; ++k) \
        Dp[k] = S2[k >> 1][k & 1] + fminf(te, m[k]); \
    STORE_ROW(i); \
} while (0)

    // ---- pipelined row loop: wave0 runs 2 rows ahead; barrier per 2 rows ----
    if (wv == 0) {
        ROW0();
        if (lane == 63) { ldsZ[0] = BIGF; ldsS[0] = S2[3].y; ldsD[0] = Dp[7]; }
        ROW_W0(1);
    }
    __syncthreads();
    for (int kk = 1; kk < 16; ++kk) {
        if (wv == 0) {
            ROW_W0(2 * kk);
            ROW_W0(2 * kk + 1);
        } else {
            const int i0 = 2 * kk - 2, i1 = 2 * kk - 1;
            if (kk == 1) {
                ROW0();
                STORE_ROW(0);
                float Z0b = ldsZ[1], Sbb = ldsS[1], Dbb = ldsD[0];
                ROW_W1(1, Z0b, Sbb, Dbb);
            } else {
                float Z0a = ldsZ[i0], Sba = ldsS[i0], Dba = ldsD[i0 - 1];
                float Z0b = ldsZ[i1], Sbb = ldsS[i1], Dbb = ldsD[i1 - 1];
                ROW_W1(i0, Z0a, Sba, Dba);
                ROW_W1(i1, Z0b, Sbb, Dbb);
            }
        }
        __syncthreads();
    }
    if (wv == 1) {   // drain: rows 30, 31 (wave0 published them in kk=15)
        float Z0a = ldsZ[30], Sba = ldsS[30], Dba = ldsD[29];
        float Z0b = ldsZ[31], Sbb = ldsS[31], Dbb = ldsD[30];
        ROW_W1(30, Z0a, Sba, Dba);
        ROW_W1(31, Z0b, Sbb, Dbb);
    }
}

extern "C" void kernel_launch(void* const* d_in, const int* in_sizes, int n_in,
                              void* d_out, int out_size, void* d_ws, size_t ws_size,
                              hipStream_t stream) {
    const float* x     = (const float*)d_in[0];   // [32,12,1024] f32
    const float* patts = (const float*)d_in[1];   // [32,12,32]   f32
    float* out         = (float*)d_out;           // [32,32,32,32] f32
    dtw_kernel<<<dim3(1024), dim3(128), 0, stream>>>(x, patts, out);
}

// Round 3
// 78.640 us; speedup vs baseline: 1.0292x; 1.0292x over previous
//
#include <hip/hip_runtime.h>

// DTW via min-plus scan for MI355X (gfx950). Round 17 (= r16 resubmitted;
// prior bench died on container acquisition, not kernel verification).
// B=32, N=32, D=12, P=32, L=1024, L_OUT=32, RHO=1 => w=1.
// Model (fit r13/r14/r15): kernel is ISSUE-bound ~10us; harness floor ~68us
// (268MB re-poison fill at 83% HBM peak sits in the timed graph).
// Evidence: FP32 peak arithmetic => v_pk_fma_f32 is 4cy/wave64 on CDNA4
// (no gain over plain v_fma_f32) -- explains r13~r14; r15's +13% tracked
// its +22% per-SIMD issue, not stall hiding.
// r16/r17 vs r14 (pure issue trims, same validated structure):
//   (1) plain v_fma_f32 with readlane-SGPR operand: removes the ~26
//       v_mov/row that VOP3P 64-bit broadcast pairs (bc2) required;
//   (2) classic GCN 6-op wave64 scans: row_shr 1/2/4/8 + row_bcast15
//       (row_mask 0xA) + row_bcast31 (row_mask 0xC) -- replaces the
//       3x(readlane+cndmask+min/add) combine tail;
//   (3) scalar register arrays (no v2f pack/unpack at boundaries).

#define BIGF 1e30f
#define LL   1024
#define LOUT 32

using v4f = __attribute__((ext_vector_type(4))) float;

template<int CTRL>
__device__ __forceinline__ float dpp_self(float v) {   // invalid lanes keep own
    return __int_as_float(__builtin_amdgcn_update_dpp(
        __float_as_int(v), __float_as_int(v), CTRL, 0xF, 0xF, false));
}
template<int CTRL>
__device__ __forceinline__ float dpp_zero(float v) {   // invalid lanes get 0
    return __int_as_float(__builtin_amdgcn_update_dpp(
        0, __float_as_int(v), CTRL, 0xF, 0xF, false));
}
template<int CTRL, int RM>
__device__ __forceinline__ float dpp_self_rm(float v) { // masked rows keep own
    return __int_as_float(__builtin_amdgcn_update_dpp(
        __float_as_int(v), __float_as_int(v), CTRL, RM, 0xF, false));
}
template<int CTRL, int RM>
__device__ __forceinline__ float dpp_zero_rm(float v) { // masked rows get 0
    return __int_as_float(__builtin_amdgcn_update_dpp(
        0, __float_as_int(v), CTRL, RM, 0xF, false));
}
// validated r2-r15: whole-wave shift right 1 lane; lane 0 <- 0
__device__ __forceinline__ float wshr1z(float v) {
    return __int_as_float(__builtin_amdgcn_update_dpp(
        0, __float_as_int(v), 0x138 /*wave_shr:1*/, 0xF, 0xF, false));
}
__device__ __forceinline__ float rdlane(float v, int l) {
    return __int_as_float(__builtin_amdgcn_readlane(__float_as_int(v), l));
}

// inclusive wave64 min-scan, classic GCN 6-op form.
// After row_shr 1/2/4/8 each lane holds its row-of-16 inclusive min.
// row_bcast15 (rows 1,3 <- lane 15/47 of previous row) then
// row_bcast31 (rows 2,3 <- lane 31 = rows0-1 total) complete the scan.
// min identity: masked/invalid lanes keep own value (fmin(t,t)=t).
__device__ __forceinline__ float scan_min64(float t) {
    t = fminf(t, dpp_self<0x111>(t));            // row_shr:1
    t = fminf(t, dpp_self<0x112>(t));            // row_shr:2
    t = fminf(t, dpp_self<0x114>(t));            // row_shr:4
    t = fminf(t, dpp_self<0x118>(t));            // row_shr:8
    t = fminf(t, dpp_self_rm<0x142, 0xA>(t));    // row_bcast:15, rows 1,3
    t = fminf(t, dpp_self_rm<0x143, 0xC>(t));    // row_bcast:31, rows 2,3
    return t;
}
// inclusive wave64 add-scan, same shape; add identity: masked lanes get 0.
__device__ __forceinline__ float scan_add64(float t) {
    t += dpp_zero<0x111>(t);
    t += dpp_zero<0x112>(t);
    t += dpp_zero<0x114>(t);
    t += dpp_zero<0x118>(t);
    t += dpp_zero_rm<0x142, 0xA>(t);
    t += dpp_zero_rm<0x143, 0xC>(t);
    return t;
}

__global__ __launch_bounds__(64)
__attribute__((amdgpu_waves_per_eu(1, 1)))   // 1 wave/EU: full register file
void dtw_kernel(const float* __restrict__ x, const float* __restrict__ patts,
                float* __restrict__ out) {
    const int lane = threadIdx.x;          // lane owns cols [16*lane, 16*lane+16)
    const bool l0  = (lane == 0);
    const int blk  = blockIdx.x;           // 0..1023 = (b,n)
    const int b    = blk >> 5, n = blk & 31;
    const float* __restrict__ xb = x + b * (12 * LL);
    const float* __restrict__ pn = patts + n * (12 * 32);

    // ---- pattern params into registers: lane r (r&31) holds row r ----
    float prm[12], p2r;
    {
        const int r = lane & 31;
        float s2 = 0.f;
#pragma unroll
        for (int d = 0; d < 12; ++d) {
            float v = pn[d * 32 + r];
            s2 = fmaf(v, v, s2);
            prm[d] = -2.0f * v;
        }
        p2r = s2;
    }

    // ---- x slice -> scalar regs (coalesced 16B/lane loads) ----
    float SX[12][16];
#pragma unroll
    for (int d = 0; d < 12; ++d) {
#pragma unroll
        for (int c = 0; c < 4; ++c) {
            v4f v = *(const v4f*)(xb + d * LL + 16 * lane + 4 * c);
            SX[d][4 * c + 0] = v.x;
            SX[d][4 * c + 1] = v.y;
            SX[d][4 * c + 2] = v.z;
            SX[d][4 * c + 3] = v.w;
        }
    }
    // x^2 from raw values
    float SX2[16];
#pragma unroll
    for (int k = 0; k < 16; ++k) {
        float t = SX[0][k] * SX[0][k];
#pragma unroll
        for (int d = 1; d < 12; ++d) t = fmaf(SX[d][k], SX[d][k], t);
        SX2[k] = t;
    }
    // ---- inclusive prefix sums: intra-lane serial + dpp add-scan ----
#pragma unroll
    for (int d = 0; d < 12; ++d) {
        float run = 0.f;
#pragma unroll
        for (int k = 0; k < 16; ++k) { run += SX[d][k]; SX[d][k] = run; }
        float ex = scan_add64(run) - run;   // exclusive lane offset
#pragma unroll
        for (int k = 0; k < 16; ++k) SX[d][k] += ex;
    }
    {
        float run = 0.f;
#pragma unroll
        for (int k = 0; k < 16; ++k) { run += SX2[k]; SX2[k] = run; }
        float ex = scan_add64(run) - run;
#pragma unroll
        for (int k = 0; k < 16; ++k) SX2[k] += ex;
    }
    float jp1[16];
#pragma unroll
    for (int k = 0; k < 16; ++k) jp1[k] = (float)(16 * lane + k + 1);

    float S[16], Dp[16];

    // ---- row 0: D = S(row 0) ----
    {
        float pv[12], p2u;
#pragma unroll
        for (int d = 0; d < 12; ++d) pv[d] = rdlane(prm[d], 0);
        p2u = rdlane(p2r, 0);
#pragma unroll
        for (int k = 0; k < 16; ++k) S[k] = fmaf(p2u, jp1[k], SX2[k]);
#pragma unroll
        for (int d = 0; d < 12; ++d)
#pragma unroll
            for (int k = 0; k < 16; ++k) S[k] = fmaf(pv[d], SX[d][k], S[k]);
#pragma unroll
        for (int k = 0; k < 16; ++k) Dp[k] = S[k];
        if (lane >= 62) {
            float* ob = out + blk * (32 * LOUT) + (lane - 62) * 16;
#pragma unroll
            for (int c = 0; c < 4; ++c) {
                v4f v = {Dp[4*c], Dp[4*c+1], Dp[4*c+2], Dp[4*c+3]};
                *(v4f*)(ob + 4 * c) = v;
            }
        }
    }

    // ---- rows 1..31: zero LDS, zero barriers; unroll 2 for cross-row ILP ----
#pragma unroll 2
    for (int i = 1; i < 32; ++i) {
        // row params via readlane (uniform index -> SGPR, free fma operand)
        float pv[12], p2u;
#pragma unroll
        for (int d = 0; d < 12; ++d) pv[d] = rdlane(prm[d], i);
        p2u = rdlane(p2r, i);

        // S(row i): 13 plain v_fma_f32 per column, SGPR broadcast operand
#pragma unroll
        for (int k = 0; k < 16; ++k) S[k] = fmaf(p2u, jp1[k], SX2[k]);
#pragma unroll
        for (int d = 0; d < 12; ++d)
#pragma unroll
            for (int k = 0; k < 16; ++k) S[k] = fmaf(pv[d], SX[d][k], S[k]);

        // boundary values from the left neighbor
        float dsh = wshr1z(Dp[15]); dsh = l0 ? BIGF : dsh;  // D_prev[j-1] at k=0
        float se  = wshr1z(S[15]);                          // S[j-1] at k=0 (lane0->0)

        // z[k] = min(Dprev[k-1],Dprev[k]) - S[k-1]; intra-lane inclusive min m
        float m[16];
        m[0] = fminf(dsh, Dp[0]) - se;
#pragma unroll
        for (int k = 1; k < 16; ++k)
            m[k] = fminf(m[k-1], fminf(Dp[k-1], Dp[k]) - S[k-1]);

        // cross-lane inclusive min-scan of lane totals, then exclusive
        float t  = scan_min64(m[15]);
        float te = wshr1z(t); te = l0 ? BIGF : te;

#pragma unroll
        for (int k = 0; k < 16; ++k)
            Dp[k] = S[k] + fminf(te, m[k]);

        if (lane >= 62) {
            float* ob = out + blk * (32 * LOUT) + (lane - 62) * 16;
#pragma unroll
            for (int c = 0; c < 4; ++c) {
                v4f v = {Dp[4*c], Dp[4*c+1], Dp[4*c+2], Dp[4*c+3]};
                *(v4f*)(ob + i * 32 + 4 * c) = v;
            }
        }
    }
}

extern "C" void kernel_launch(void* const* d_in, const int* in_sizes, int n_in,
                              void* d_out, int out_size, void* d_ws, size_t ws_size,
                              hipStream_t stream) {
    const float* x     = (const float*)d_in[0];   // [32,12,1024] f32
    const float* patts = (const float*)d_in[1];   // [32,12,32]   f32
    float* out         = (float*)d_out;           // [32,32,32,32] f32
    dtw_kernel<<<dim3(1024), dim3(64), 0, stream>>>(x, patts, out);
}

// Round 4
// 78.588 us; speedup vs baseline: 1.0299x; 1.0007x over previous
//
#include <hip/hip_runtime.h>

// DTW via min-plus scan for MI355X (gfx950). Round 18.
// B=32, N=32, D=12, P=32, L=1024, L_OUT=32, RHO=1 => w=1.
// Model after r14-r17: row loop is DEPENDENCY-CHAIN bound at 1 wave/SIMD;
// issue-count changes (r14 -30%, r15 +22%, r17 -13%) all failed to move
// the clock except r15's barriers-in-chain regression. r18 attacks the
// chain itself:
//   (1) depth cut: serial 15-step m-chain -> z[] (off-chain) + groups-of-4
//       local min (depth 3) + group prefix e1..e3 (depth 2), with group
//       offsets folded into te (3 ops, no combine pass). ~27 -> ~18 deps/row.
//       fmin is exactly associative: bit-identical results.
//   (2) forced overlap: next row's 222-fma S-compute is source-placed in 4
//       chunks BETWEEN chain stages, so in-order issue fills the stall
//       shadows by construction (the scheduler provably wasn't doing this:
//       issue trims were invisible).

#define BIGF 1e30f
#define LL   1024
#define LOUT 32

using v4f = __attribute__((ext_vector_type(4))) float;

template<int CTRL>
__device__ __forceinline__ float dpp_self(float v) {   // invalid lanes keep own
    return __int_as_float(__builtin_amdgcn_update_dpp(
        __float_as_int(v), __float_as_int(v), CTRL, 0xF, 0xF, false));
}
template<int CTRL>
__device__ __forceinline__ float dpp_zero(float v) {   // invalid lanes get 0
    return __int_as_float(__builtin_amdgcn_update_dpp(
        0, __float_as_int(v), CTRL, 0xF, 0xF, false));
}
template<int CTRL, int RM>
__device__ __forceinline__ float dpp_self_rm(float v) { // masked rows keep own
    return __int_as_float(__builtin_amdgcn_update_dpp(
        __float_as_int(v), __float_as_int(v), CTRL, RM, 0xF, false));
}
template<int CTRL, int RM>
__device__ __forceinline__ float dpp_zero_rm(float v) { // masked rows get 0
    return __int_as_float(__builtin_amdgcn_update_dpp(
        0, __float_as_int(v), CTRL, RM, 0xF, false));
}
// validated r2-r17: whole-wave shift right 1 lane; lane 0 <- 0
__device__ __forceinline__ float wshr1z(float v) {
    return __int_as_float(__builtin_amdgcn_update_dpp(
        0, __float_as_int(v), 0x138 /*wave_shr:1*/, 0xF, 0xF, false));
}
__device__ __forceinline__ float rdlane(float v, int l) {
    return __int_as_float(__builtin_amdgcn_readlane(__float_as_int(v), l));
}

// inclusive wave64 min-scan, 6-op GCN form (validated r17)
__device__ __forceinline__ float scan_min64(float t) {
    t = fminf(t, dpp_self<0x111>(t));            // row_shr:1
    t = fminf(t, dpp_self<0x112>(t));            // row_shr:2
    t = fminf(t, dpp_self<0x114>(t));            // row_shr:4
    t = fminf(t, dpp_self<0x118>(t));            // row_shr:8
    t = fminf(t, dpp_self_rm<0x142, 0xA>(t));    // row_bcast:15, rows 1,3
    t = fminf(t, dpp_self_rm<0x143, 0xC>(t));    // row_bcast:31, rows 2,3
    return t;
}
// inclusive wave64 add-scan (validated r17)
__device__ __forceinline__ float scan_add64(float t) {
    t += dpp_zero<0x111>(t);
    t += dpp_zero<0x112>(t);
    t += dpp_zero<0x114>(t);
    t += dpp_zero<0x118>(t);
    t += dpp_zero_rm<0x142, 0xA>(t);
    t += dpp_zero_rm<0x143, 0xC>(t);
    return t;
}

__global__ __launch_bounds__(64)
__attribute__((amdgpu_waves_per_eu(1, 1)))   // 1 wave/EU: full register file
void dtw_kernel(const float* __restrict__ x, const float* __restrict__ patts,
                float* __restrict__ out) {
    const int lane = threadIdx.x;          // lane owns cols [16*lane, 16*lane+16)
    const bool l0  = (lane == 0);
    const int blk  = blockIdx.x;           // 0..1023 = (b,n)
    const int b    = blk >> 5, n = blk & 31;
    const float* __restrict__ xb = x + b * (12 * LL);
    const float* __restrict__ pn = patts + n * (12 * 32);

    // ---- pattern params into registers: lane r (r&31) holds row r ----
    float prm[12], p2r;
    {
        const int r = lane & 31;
        float s2 = 0.f;
#pragma unroll
        for (int d = 0; d < 12; ++d) {
            float v = pn[d * 32 + r];
            s2 = fmaf(v, v, s2);
            prm[d] = -2.0f * v;
        }
        p2r = s2;
    }

    // ---- x slice -> scalar regs (coalesced 16B/lane loads) ----
    float SX[12][16];
#pragma unroll
    for (int d = 0; d < 12; ++d) {
#pragma unroll
        for (int c = 0; c < 4; ++c) {
            v4f v = *(const v4f*)(xb + d * LL + 16 * lane + 4 * c);
            SX[d][4 * c + 0] = v.x;
            SX[d][4 * c + 1] = v.y;
            SX[d][4 * c + 2] = v.z;
            SX[d][4 * c + 3] = v.w;
        }
    }
    // x^2 from raw values
    float SX2[16];
#pragma unroll
    for (int k = 0; k < 16; ++k) {
        float t = SX[0][k] * SX[0][k];
#pragma unroll
        for (int d = 1; d < 12; ++d) t = fmaf(SX[d][k], SX[d][k], t);
        SX2[k] = t;
    }
    // ---- inclusive prefix sums: intra-lane serial + dpp add-scan ----
#pragma unroll
    for (int d = 0; d < 12; ++d) {
        float run = 0.f;
#pragma unroll
        for (int k = 0; k < 16; ++k) { run += SX[d][k]; SX[d][k] = run; }
        float ex = scan_add64(run) - run;   // exclusive lane offset
#pragma unroll
        for (int k = 0; k < 16; ++k) SX[d][k] += ex;
    }
    {
        float run = 0.f;
#pragma unroll
        for (int k = 0; k < 16; ++k) { run += SX2[k]; SX2[k] = run; }
        float ex = scan_add64(run) - run;
#pragma unroll
        for (int k = 0; k < 16; ++k) SX2[k] += ex;
    }
    float jp1[16];
#pragma unroll
    for (int k = 0; k < 16; ++k) jp1[k] = (float)(16 * lane + k + 1);

    float SA[16], SB[16], Dp[16];

// ---- S-compute chunks (next row), placed between chain stages ----
#define SN_CHUNK0(SN, inx) do { \
    float p2u = rdlane(p2r, (inx)); \
    _Pragma("unroll") for (int k = 0; k < 16; ++k) \
        SN[k] = fmaf(p2u, jp1[k], SX2[k]); \
    _Pragma("unroll") for (int d = 0; d < 3; ++d) { \
        float pv = rdlane(prm[d], (inx)); \
        _Pragma("unroll") for (int k = 0; k < 16; ++k) \
            SN[k] = fmaf(pv, SX[d][k], SN[k]); \
    } \
} while (0)

#define SN_CHUNKD(SN, inx, d0, d1) do { \
    _Pragma("unroll") for (int d = (d0); d < (d1); ++d) { \
        float pv = rdlane(prm[d], (inx)); \
        _Pragma("unroll") for (int k = 0; k < 16; ++k) \
            SN[k] = fmaf(pv, SX[d][k], SN[k]); \
    } \
} while (0)

#define COMPUTE_S_FULL(SN, inx) do { \
    SN_CHUNK0(SN, (inx)); SN_CHUNKD(SN, (inx), 3, 12); \
} while (0)

#define STORE_ROW(i) do { \
    if (lane >= 62) { \
        float* ob = out + blk * (32 * LOUT) + (lane - 62) * 16; \
        _Pragma("unroll") for (int c = 0; c < 4; ++c) { \
            v4f v = {Dp[4*c], Dp[4*c+1], Dp[4*c+2], Dp[4*c+3]}; \
            *(v4f*)(ob + (i) * 32 + 4 * c) = v; \
        } \
    } \
} while (0)

// One DP row, chain-minimized; optionally computes next row's S into SN.
// z[k] = min(Dp[k-1],Dp[k]) - SC[k-1]   (off-chain, independent)
// groups of 4: local serial min (depth 3); e1..e3 group prefix (depth 2);
// m15 = min(e3, z[15]); wave scan; te; Dp[k] = SC[k] + min(te_g, zloc[k]).
// All fmin trees exactly associative => bit-identical to serial chain.
#define ROW_CHAIN(i, SC, SN, CN) do { \
    float dsh = wshr1z(Dp[15]); dsh = l0 ? BIGF : dsh; \
    float se  = wshr1z(SC[15]); \
    float z[16]; \
    z[0] = fminf(dsh, Dp[0]) - se; \
    _Pragma("unroll") for (int k = 1; k < 16; ++k) \
        z[k] = fminf(Dp[k-1], Dp[k]) - SC[k-1]; \
    if (CN) { SN_CHUNK0(SN, (i) + 1); } \
    _Pragma("unroll") for (int g = 0; g < 4; ++g) { \
        _Pragma("unroll") for (int j = 1; j < 4; ++j) \
            z[4*g + j] = fminf(z[4*g + j - 1], z[4*g + j]); \
    } \
    if (CN) { SN_CHUNKD(SN, (i) + 1, 3, 6); } \
    float e1 = z[3]; \
    float e2 = fminf(e1, z[7]); \
    float e3 = fminf(e2, z[11]); \
    float m15 = fminf(e3, z[15]); \
    float t = scan_min64(m15); \
    if (CN) { SN_CHUNKD(SN, (i) + 1, 6, 9); } \
    float te = wshr1z(t); te = l0 ? BIGF : te; \
    float te1 = fminf(te, e1), te2 = fminf(te, e2), te3 = fminf(te, e3); \
    _Pragma("unroll") for (int k = 0;  k < 4;  ++k) Dp[k] = SC[k] + fminf(te,  z[k]); \
    _Pragma("unroll") for (int k = 4;  k < 8;  ++k) Dp[k] = SC[k] + fminf(te1, z[k]); \
    _Pragma("unroll") for (int k = 8;  k < 12; ++k) Dp[k] = SC[k] + fminf(te2, z[k]); \
    _Pragma("unroll") for (int k = 12; k < 16; ++k) Dp[k] = SC[k] + fminf(te3, z[k]); \
    if (CN) { SN_CHUNKD(SN, (i) + 1, 9, 12); } \
    STORE_ROW(i); \
} while (0)

    // ---- row 0: D = S(row 0) ----
    COMPUTE_S_FULL(SA, 0);
#pragma unroll
    for (int k = 0; k < 16; ++k) Dp[k] = SA[k];
    STORE_ROW(0);
    COMPUTE_S_FULL(SB, 1);   // prime the pipeline: S(row 1)

    // ---- rows 1..30: 2 rows/iter, S ping-pong SA<->SB (static indexing) ----
#pragma unroll 1
    for (int kk = 0; kk < 15; ++kk) {
        const int i0 = 2 * kk + 1;
        ROW_CHAIN(i0,     SB, SA, true);   // uses S(i0),   computes S(i0+1)
        ROW_CHAIN(i0 + 1, SA, SB, true);   // uses S(i0+1), computes S(i0+2)
    }
    // ---- row 31: no next row ----
    ROW_CHAIN(31, SB, SA, false);

#undef SN_CHUNK0
#undef SN_CHUNKD
#undef COMPUTE_S_FULL
#undef STORE_ROW
#undef ROW_CHAIN
}

extern "C" void kernel_launch(void* const* d_in, const int* in_sizes, int n_in,
                              void* d_out, int out_size, void* d_ws, size_t ws_size,
                              hipStream_t stream) {
    const float* x     = (const float*)d_in[0];   // [32,12,1024] f32
    const float* patts = (const float*)d_in[1];   // [32,12,32]   f32
    float* out         = (float*)d_out;           // [32,32,32,32] f32
    dtw_kernel<<<dim3(1024), dim3(64), 0, stream>>>(x, patts, out);
}